// Round 1
// baseline (934.996 us; speedup 1.0000x reference)
//
#include <hip/hip_runtime.h>
#include <cstdint>
#include <cstddef>

#define Bn 8
#define Cn 64
#define HWn 65536

// ws float offsets
#define WS_Z 0
#define WS_XPOOL 8
#define WS_A 520
#define WS_WA 1032
#define WS_M1 1544
#define WS_M2 5640

__device__ __forceinline__ float blk_reduce(float v, float* red) {
#pragma unroll
  for (int off = 32; off; off >>= 1) v += __shfl_down(v, off, 64);
  int lane = threadIdx.x & 63, wid = threadIdx.x >> 6;
  if (lane == 0) red[wid] = v;
  __syncthreads();
  float s = 0.f;
  if (threadIdx.x == 0) {
    int nw = blockDim.x >> 6;
    for (int w = 0; w < nw; ++w) s += red[w];
  }
  return s;
}

// K1a: e[b,n] = exp(Wk . x[b,:,n])  -> out plane(b,1);  Z[b] += block sums
__global__ __launch_bounds__(256) void k1a(const float* __restrict__ x, const float* __restrict__ Wk,
                                           float* __restrict__ out, float* __restrict__ ws) {
  int idx = blockIdx.x * 256 + threadIdx.x;
  int b = idx >> 16, n = idx & (HWn - 1);
  const float* xp = x + (size_t)b * Cn * HWn + n;
  float k = 0.f;
#pragma unroll
  for (int c = 0; c < Cn; ++c) k += Wk[c] * xp[(size_t)c * HWn];
  float e = __expf(k);
  out[((size_t)(b * Cn + 1)) * HWn + n] = e;
  __shared__ float red[4];
  float s = blk_reduce(e, red);
  if (threadIdx.x == 0) atomicAdd(&ws[WS_Z + b], s);
}

// K1b: xpool[b,c] = sum_n x[b,c,n] * e[b,n]
__global__ __launch_bounds__(256) void k1b(const float* __restrict__ x, const float* __restrict__ out,
                                           float* __restrict__ ws) {
  int blk = blockIdx.x;
  int b = blk >> 8, c = (blk >> 2) & 63, seg = blk & 3;
  const float4* xr = (const float4*)(x + ((size_t)(b * Cn + c)) * HWn + seg * 16384);
  const float4* er = (const float4*)(out + ((size_t)(b * Cn + 1)) * HWn + seg * 16384);
  float acc = 0.f;
#pragma unroll 4
  for (int j = 0; j < 16; ++j) {
    float4 xv = xr[threadIdx.x + j * 256];
    float4 ev = er[threadIdx.x + j * 256];
    acc += xv.x * ev.x + xv.y * ev.y + xv.z * ev.z + xv.w * ev.w;
  }
  __shared__ float red[4];
  float s = blk_reduce(acc, red);
  if (threadIdx.x == 0) atomicAdd(&ws[WS_XPOOL + b * Cn + c], s);
}

// K2a: per-batch a = softmax(Wup @ Wq @ (xpool/Z)); wa = Wq^T a  (1 block, 64 threads)
__global__ void k2a(const float* __restrict__ Wq, const float* __restrict__ Wup, float* __restrict__ ws) {
  int t = threadIdx.x;  // 0..63
  __shared__ float xp_s[64], t1[64], a_s[64];
  for (int b = 0; b < Bn; ++b) {
    float Zb = ws[WS_Z + b];
    xp_s[t] = ws[WS_XPOOL + b * 64 + t] / Zb;
    __syncthreads();
    float acc = 0.f;
    for (int i = 0; i < 64; ++i) acc += Wq[t * 64 + i] * xp_s[i];
    t1[t] = acc;
    __syncthreads();
    float acc2 = 0.f;
    for (int i = 0; i < 64; ++i) acc2 += Wup[t * 64 + i] * t1[i];
    float m = acc2;
#pragma unroll
    for (int off = 32; off; off >>= 1) m = fmaxf(m, __shfl_xor(m, off, 64));
    float e = __expf(acc2 - m);
    float ssum = e;
#pragma unroll
    for (int off = 32; off; off >>= 1) ssum += __shfl_xor(ssum, off, 64);
    float av = e / ssum;
    ws[WS_A + b * 64 + t] = av;
    a_s[t] = av;
    __syncthreads();
    float wav = 0.f;
    for (int o = 0; o < 64; ++o) wav += a_s[o] * Wq[o * 64 + t];
    ws[WS_WA + b * 64 + t] = wav;
    __syncthreads();
  }
}

// K2b: block 0 -> M1 = Wout@Wv_spa ; block j=1..8 -> M2[b=j-1] = Wout@diag(a[b])@Wv_spe
__global__ __launch_bounds__(256) void k2b(const float* __restrict__ Wout, const float* __restrict__ Wv_spa,
                                           const float* __restrict__ Wv_spe, float* __restrict__ ws) {
  __shared__ float A[4096], Bm[4096];
  int j = blockIdx.x;
  for (int idx = threadIdx.x; idx < 4096; idx += 256) {
    A[idx] = Wout[idx];
    if (j == 0)
      Bm[idx] = Wv_spa[idx];
    else
      Bm[idx] = ws[WS_A + (j - 1) * 64 + (idx >> 6)] * Wv_spe[idx];
  }
  __syncthreads();
  float* dst = (j == 0) ? (ws + WS_M1) : (ws + WS_M2 + (size_t)(j - 1) * 4096);
  for (int oi = threadIdx.x; oi < 4096; oi += 256) {
    int o = oi >> 6, i = oi & 63;
    float acc = 0.f;
#pragma unroll
    for (int c = 0; c < 64; ++c) acc += A[o * 64 + c] * Bm[c * 64 + i];
    dst[oi] = acc;
  }
}

// K3: attn_spa[b,n] = wa[b] . x[b,:,n]  -> out plane(b,2)
__global__ __launch_bounds__(256) void k3(const float* __restrict__ x, const float* __restrict__ ws,
                                          float* __restrict__ out) {
  int idx = blockIdx.x * 256 + threadIdx.x;
  int b = idx >> 16, n = idx & (HWn - 1);
  const float* xp = x + (size_t)b * Cn * HWn + n;
  const float* wa = ws + WS_WA + b * 64;
  float k = 0.f;
#pragma unroll
  for (int c = 0; c < Cn; ++c) k += wa[c] * xp[(size_t)c * HWn];
  out[((size_t)(b * Cn + 2)) * HWn + n] = k;
}

// Kconv: s = sigmoid(conv7x7(attn_spa)) ; read plane(b,2), write plane(b,0)
__global__ __launch_bounds__(256) void kconv(const float* __restrict__ Wn, float* out) {
  __shared__ float t[38 * 38];
  int blk = blockIdx.x;
  int b = blk >> 6, ty = (blk >> 3) & 7, tx = blk & 7;
  const float* src = out + ((size_t)(b * Cn + 2)) * HWn;
  float* dstp = out + ((size_t)(b * Cn + 0)) * HWn;
  for (int idx = threadIdx.x; idx < 38 * 38; idx += 256) {
    int ly = idx / 38, lx = idx - ly * 38;
    int gy = ty * 32 + ly - 3, gx = tx * 32 + lx - 3;
    float v = 0.f;
    if (gy >= 0 && gy < 256 && gx >= 0 && gx < 256) v = src[gy * 256 + gx];
    t[idx] = v;
  }
  __syncthreads();
#pragma unroll
  for (int q = 0; q < 4; ++q) {
    int pix = threadIdx.x + q * 256;
    int r = pix >> 5, col = pix & 31;
    float acc = 0.f;
#pragma unroll
    for (int dy = 0; dy < 7; ++dy)
#pragma unroll
      for (int dx = 0; dx < 7; ++dx)
        acc += t[(r + dy) * 38 + (col + dx)] * Wn[dy * 7 + dx];
    float sg = 1.f / (1.f + __expf(-acc));
    dstp[(ty * 32 + r) * 256 + tx * 32 + col] = sg;
  }
}

// K4: out[b,o,n] = s[b,n]*(M1 x)[o] + (M2[b] x)[o]
__global__ __launch_bounds__(256) void k4(const float* __restrict__ x, const float* __restrict__ ws,
                                          float* out) {
  int idx = blockIdx.x * 256 + threadIdx.x;
  int b = idx >> 16, n = idx & (HWn - 1);
  const float* xp = x + (size_t)b * Cn * HWn + n;
  float s = out[((size_t)(b * Cn)) * HWn + n];  // plane(b,0), written by kconv; owner-thread read
  float xv[64];
#pragma unroll
  for (int c = 0; c < Cn; ++c) xv[c] = xp[(size_t)c * HWn];
  const float* M1 = ws + WS_M1;
  const float* M2 = ws + WS_M2 + (size_t)b * 4096;
  float* op = out + ((size_t)(b * Cn)) * HWn + n;
  for (int o = 0; o < 64; ++o) {
    float a1 = 0.f, a2 = 0.f;
#pragma unroll
    for (int i = 0; i < 64; ++i) {
      a1 += M1[o * 64 + i] * xv[i];
      a2 += M2[o * 64 + i] * xv[i];
    }
    op[(size_t)o * HWn] = s * a1 + a2;
  }
}

extern "C" void kernel_launch(void* const* d_in, const int* in_sizes, int n_in,
                              void* d_out, int out_size, void* d_ws, size_t ws_size,
                              hipStream_t stream) {
  const float* x      = (const float*)d_in[0];
  const float* Wq     = (const float*)d_in[1];
  const float* Wk     = (const float*)d_in[2];
  const float* Wv_spe = (const float*)d_in[3];
  const float* Wv_spa = (const float*)d_in[4];
  const float* Wup    = (const float*)d_in[5];
  const float* Wout   = (const float*)d_in[6];
  const float* Wn     = (const float*)d_in[7];
  float* out = (float*)d_out;
  float* ws  = (float*)d_ws;

  hipMemsetAsync(ws, 0, 520 * sizeof(float), stream);          // Z + xpool accumulators
  k1a<<<2048, 256, 0, stream>>>(x, Wk, out, ws);
  k1b<<<2048, 256, 0, stream>>>(x, out, ws);
  k2a<<<1, 64, 0, stream>>>(Wq, Wup, ws);
  k2b<<<9, 256, 0, stream>>>(Wout, Wv_spa, Wv_spe, ws);
  k3<<<2048, 256, 0, stream>>>(x, ws, out);
  kconv<<<512, 256, 0, stream>>>(Wn, out);
  k4<<<2048, 256, 0, stream>>>(x, ws, out);
}

// Round 2
// 547.068 us; speedup vs baseline: 1.7091x; 1.7091x over previous
//
#include <hip/hip_runtime.h>
#include <cstdint>
#include <cstddef>

#define Bn 8
#define Cn 64
#define HWn 65536

// ws float offsets
#define WS_Z 0
#define WS_XPOOL 8
#define WS_A 520
#define WS_WA 1032
#define WS_M1 1544
#define WS_M2 5640

// K1 fused: e = exp(Wk.x) kept in LDS; Z[b] += sum(e); xpool[b,c] += sum_n x*e
// grid 512 (b*64 tiles of 1024 pixels), 256 threads, 4 pixels/thread
__global__ __launch_bounds__(256) void k1(const float* __restrict__ x, const float* __restrict__ Wk,
                                          float* __restrict__ ws) {
  __shared__ float e_s[1024];
  __shared__ float red[4];
  int blk = blockIdx.x;
  int b = blk >> 6;
  int base = (blk & 63) << 10;
  int t = threadIdx.x;
  const float* xb = x + (size_t)b * Cn * HWn;
  int n0 = base + t * 4;

  // phase 1: k-dot + exp
  float4 k = {0.f, 0.f, 0.f, 0.f};
#pragma unroll
  for (int c = 0; c < Cn; ++c) {
    float4 xv = *(const float4*)(xb + (size_t)c * HWn + n0);
    float wkc = Wk[c];
    k.x += wkc * xv.x; k.y += wkc * xv.y; k.z += wkc * xv.z; k.w += wkc * xv.w;
  }
  float4 e;
  e.x = __expf(k.x); e.y = __expf(k.y); e.z = __expf(k.z); e.w = __expf(k.w);
  *(float4*)(e_s + t * 4) = e;
  float part = e.x + e.y + e.z + e.w;
#pragma unroll
  for (int off = 32; off; off >>= 1) part += __shfl_down(part, off, 64);
  int lane = t & 63, wid = t >> 6;
  if (lane == 0) red[wid] = part;
  __syncthreads();  // also publishes e_s
  if (t == 0) atomicAdd(&ws[WS_Z + b], red[0] + red[1] + red[2] + red[3]);

  // phase 2: xpool partials (x re-read hits L2)
#pragma unroll 4
  for (int j = 0; j < 16; ++j) {
    int c = wid * 16 + j;
    const float* xc = xb + (size_t)c * HWn + base;
    float acc = 0.f;
#pragma unroll
    for (int rep = 0; rep < 4; ++rep) {
      int idx = rep * 256 + lane;
      acc += xc[idx] * e_s[idx];
    }
#pragma unroll
    for (int off = 32; off; off >>= 1) acc += __shfl_down(acc, off, 64);
    if (lane == 0) atomicAdd(&ws[WS_XPOOL + b * Cn + c], acc);
  }
}

// K2a: per-batch a = softmax(Wup @ Wq @ (xpool/Z)); wa = Wq^T a  (1 block, 64 threads)
__global__ void k2a(const float* __restrict__ Wq, const float* __restrict__ Wup, float* __restrict__ ws) {
  int t = threadIdx.x;  // 0..63
  __shared__ float xp_s[64], t1[64], a_s[64];
  for (int b = 0; b < Bn; ++b) {
    float Zb = ws[WS_Z + b];
    xp_s[t] = ws[WS_XPOOL + b * 64 + t] / Zb;
    __syncthreads();
    float acc = 0.f;
    for (int i = 0; i < 64; ++i) acc += Wq[t * 64 + i] * xp_s[i];
    t1[t] = acc;
    __syncthreads();
    float acc2 = 0.f;
    for (int i = 0; i < 64; ++i) acc2 += Wup[t * 64 + i] * t1[i];
    float m = acc2;
#pragma unroll
    for (int off = 32; off; off >>= 1) m = fmaxf(m, __shfl_xor(m, off, 64));
    float e = __expf(acc2 - m);
    float ssum = e;
#pragma unroll
    for (int off = 32; off; off >>= 1) ssum += __shfl_xor(ssum, off, 64);
    float av = e / ssum;
    ws[WS_A + b * 64 + t] = av;
    a_s[t] = av;
    __syncthreads();
    float wav = 0.f;
    for (int o = 0; o < 64; ++o) wav += a_s[o] * Wq[o * 64 + t];
    ws[WS_WA + b * 64 + t] = wav;
    __syncthreads();
  }
}

// K2b: block 0 -> M1 = Wout@Wv_spa ; block j=1..8 -> M2[b=j-1] = Wout@diag(a[b])@Wv_spe
__global__ __launch_bounds__(256) void k2b(const float* __restrict__ Wout, const float* __restrict__ Wv_spa,
                                           const float* __restrict__ Wv_spe, float* __restrict__ ws) {
  __shared__ float A[4096], Bm[4096];
  int j = blockIdx.x;
  for (int idx = threadIdx.x; idx < 4096; idx += 256) {
    A[idx] = Wout[idx];
    if (j == 0)
      Bm[idx] = Wv_spa[idx];
    else
      Bm[idx] = ws[WS_A + (j - 1) * 64 + (idx >> 6)] * Wv_spe[idx];
  }
  __syncthreads();
  float* dst = (j == 0) ? (ws + WS_M1) : (ws + WS_M2 + (size_t)(j - 1) * 4096);
  for (int oi = threadIdx.x; oi < 4096; oi += 256) {
    int o = oi >> 6, i = oi & 63;
    float acc = 0.f;
#pragma unroll
    for (int c = 0; c < 64; ++c) acc += A[o * 64 + c] * Bm[c * 64 + i];
    dst[oi] = acc;
  }
}

// K3: attn_spa[b,n] = wa[b] . x[b,:,n]  -> out plane(b,2); 4 pixels/thread
__global__ __launch_bounds__(256) void k3(const float* __restrict__ x, const float* __restrict__ ws,
                                          float* __restrict__ out) {
  int blk = blockIdx.x;
  int b = blk >> 6;
  int base = (blk & 63) << 10;
  int n0 = base + threadIdx.x * 4;
  const float* xb = x + (size_t)b * Cn * HWn;
  const float* wa = ws + WS_WA + b * 64;
  float4 k = {0.f, 0.f, 0.f, 0.f};
#pragma unroll
  for (int c = 0; c < Cn; ++c) {
    float4 xv = *(const float4*)(xb + (size_t)c * HWn + n0);
    float wac = wa[c];
    k.x += wac * xv.x; k.y += wac * xv.y; k.z += wac * xv.z; k.w += wac * xv.w;
  }
  *(float4*)(out + ((size_t)(b * Cn + 2)) * HWn + n0) = k;
}

// Kconv: s = sigmoid(conv7x7(attn_spa)) ; read plane(b,2), write plane(b,0)
__global__ __launch_bounds__(256) void kconv(const float* __restrict__ Wn, float* out) {
  __shared__ float t[38 * 38];
  int blk = blockIdx.x;
  int b = blk >> 6, ty = (blk >> 3) & 7, tx = blk & 7;
  const float* src = out + ((size_t)(b * Cn + 2)) * HWn;
  float* dstp = out + ((size_t)(b * Cn + 0)) * HWn;
  for (int idx = threadIdx.x; idx < 38 * 38; idx += 256) {
    int ly = idx / 38, lx = idx - ly * 38;
    int gy = ty * 32 + ly - 3, gx = tx * 32 + lx - 3;
    float v = 0.f;
    if (gy >= 0 && gy < 256 && gx >= 0 && gx < 256) v = src[gy * 256 + gx];
    t[idx] = v;
  }
  __syncthreads();
#pragma unroll
  for (int q = 0; q < 4; ++q) {
    int pix = threadIdx.x + q * 256;
    int r = pix >> 5, col = pix & 31;
    float acc = 0.f;
#pragma unroll
    for (int dy = 0; dy < 7; ++dy)
#pragma unroll
      for (int dx = 0; dx < 7; ++dx)
        acc += t[(r + dy) * 38 + (col + dx)] * Wn[dy * 7 + dx];
    float sg = 1.f / (1.f + __expf(-acc));
    dstp[(ty * 32 + r) * 256 + tx * 32 + col] = sg;
  }
}

// K4: out[b,o,n] = s[b,n]*(M1 x)[o] + (M2[b] x)[o]
// M1,M2 staged transposed in LDS ([i][o], row stride 68). 4 pixels/thread,
// 4 o-chunks of 16 (acc = 16 float4 = 64 VGPRs).
#define MSTRIDE 68
__global__ __launch_bounds__(256) void k4(const float* __restrict__ x, const float* __restrict__ ws,
                                          float* out) {
  __shared__ float M1T[64 * MSTRIDE];
  __shared__ float M2T[64 * MSTRIDE];
  int blk = blockIdx.x;
  int b = blk >> 6;
  int base = (blk & 63) << 10;
  int t = threadIdx.x;
  const float* m1g = ws + WS_M1;
  const float* m2g = ws + WS_M2 + (size_t)b * 4096;
  for (int idx = t; idx < 4096; idx += 256) {
    int o = idx >> 6, i = idx & 63;
    M1T[i * MSTRIDE + o] = m1g[idx];
    M2T[i * MSTRIDE + o] = m2g[idx];
  }
  __syncthreads();

  int n0 = base + t * 4;
  const float* xb = x + (size_t)b * Cn * HWn;
  float* op = out + ((size_t)(b * Cn)) * HWn + n0;
  float4 s4 = *(const float4*)op;  // plane(b,0) = s from kconv; owner-thread read

#pragma unroll
  for (int oc = 0; oc < 4; ++oc) {
    float4 acc[16];
#pragma unroll
    for (int o = 0; o < 16; ++o) acc[o] = make_float4(0.f, 0.f, 0.f, 0.f);
    for (int i = 0; i < 64; ++i) {
      float4 xv = *(const float4*)(xb + (size_t)i * HWn + n0);
      float4 sxv;
      sxv.x = s4.x * xv.x; sxv.y = s4.y * xv.y; sxv.z = s4.z * xv.z; sxv.w = s4.w * xv.w;
      const float* m1r = M1T + i * MSTRIDE + oc * 16;
      const float* m2r = M2T + i * MSTRIDE + oc * 16;
#pragma unroll
      for (int o = 0; o < 16; ++o) {
        float m1 = m1r[o], m2 = m2r[o];
        acc[o].x += m1 * sxv.x + m2 * xv.x;
        acc[o].y += m1 * sxv.y + m2 * xv.y;
        acc[o].z += m1 * sxv.z + m2 * xv.z;
        acc[o].w += m1 * sxv.w + m2 * xv.w;
      }
    }
#pragma unroll
    for (int o = 0; o < 16; ++o)
      *(float4*)(op + (size_t)(oc * 16 + o) * HWn) = acc[o];
  }
}

extern "C" void kernel_launch(void* const* d_in, const int* in_sizes, int n_in,
                              void* d_out, int out_size, void* d_ws, size_t ws_size,
                              hipStream_t stream) {
  const float* x      = (const float*)d_in[0];
  const float* Wq     = (const float*)d_in[1];
  const float* Wk     = (const float*)d_in[2];
  const float* Wv_spe = (const float*)d_in[3];
  const float* Wv_spa = (const float*)d_in[4];
  const float* Wup    = (const float*)d_in[5];
  const float* Wout   = (const float*)d_in[6];
  const float* Wn     = (const float*)d_in[7];
  float* out = (float*)d_out;
  float* ws  = (float*)d_ws;

  hipMemsetAsync(ws, 0, 520 * sizeof(float), stream);  // Z + xpool accumulators
  k1<<<512, 256, 0, stream>>>(x, Wk, ws);
  k2a<<<1, 64, 0, stream>>>(Wq, Wup, ws);
  k2b<<<9, 256, 0, stream>>>(Wout, Wv_spa, Wv_spe, ws);
  k3<<<512, 256, 0, stream>>>(x, ws, out);
  kconv<<<512, 256, 0, stream>>>(Wn, out);
  k4<<<512, 256, 0, stream>>>(x, ws, out);
}

// Round 3
// 531.762 us; speedup vs baseline: 1.7583x; 1.0288x over previous
//
#include <hip/hip_runtime.h>
#include <cstdint>
#include <cstddef>

#define Bn 8
#define Cn 64
#define HWn 65536

// ws float offsets
#define WS_Z 0
#define WS_XPOOL 8
#define WS_A 520
#define WS_WA 1032
#define WS_M1 1544
#define WS_M2 5640
#define WS_S 38408   // 8*65536 floats; 16B aligned (38408%4==0)

// K1 fused: e = exp(Wk.x) in LDS; Z[b] += sum(e); xpool[b,c] += sum_n x*e
// grid 1024 (b * 128 tiles of 512 px), 256 threads, 2 px/thread
__global__ __launch_bounds__(256) void k1(const float* __restrict__ x, const float* __restrict__ Wk,
                                          float* __restrict__ ws) {
  __shared__ float e_s[512];
  __shared__ float red[4];
  int blk = blockIdx.x;
  int b = blk >> 7;
  int base = (blk & 127) << 9;
  int t = threadIdx.x;
  const float* xb = x + (size_t)b * Cn * HWn;
  int n0 = base + t * 2;

  float kx = 0.f, ky = 0.f;
#pragma unroll
  for (int c = 0; c < Cn; ++c) {
    float2 xv = *(const float2*)(xb + (size_t)c * HWn + n0);
    float w = Wk[c];
    kx += w * xv.x; ky += w * xv.y;
  }
  float ex = __expf(kx), ey = __expf(ky);
  e_s[t * 2] = ex; e_s[t * 2 + 1] = ey;
  float part = ex + ey;
#pragma unroll
  for (int off = 32; off; off >>= 1) part += __shfl_down(part, off, 64);
  int lane = t & 63, wid = t >> 6;
  if (lane == 0) red[wid] = part;
  __syncthreads();  // publishes e_s + red
  if (t == 0) atomicAdd(&ws[WS_Z + b], red[0] + red[1] + red[2] + red[3]);

  // phase 2: xpool partials; each wave handles 16 channels over all 512 px
#pragma unroll 4
  for (int j = 0; j < 16; ++j) {
    int c = wid * 16 + j;
    const float* xc = xb + (size_t)c * HWn + base;
    float acc = 0.f;
#pragma unroll
    for (int rep = 0; rep < 8; ++rep) {
      int idx = rep * 64 + lane;
      acc += xc[idx] * e_s[idx];
    }
#pragma unroll
    for (int off = 32; off; off >>= 1) acc += __shfl_down(acc, off, 64);
    if (lane == 0) atomicAdd(&ws[WS_XPOOL + b * Cn + c], acc);
  }
}

// K2a: per-batch a = softmax(Wup @ Wq @ (xpool/Z)); wa = Wq^T a  (1 block, 64 threads)
__global__ void k2a(const float* __restrict__ Wq, const float* __restrict__ Wup, float* __restrict__ ws) {
  int t = threadIdx.x;  // 0..63
  __shared__ float xp_s[64], t1[64], a_s[64];
  for (int b = 0; b < Bn; ++b) {
    float Zb = ws[WS_Z + b];
    xp_s[t] = ws[WS_XPOOL + b * 64 + t] / Zb;
    __syncthreads();
    float acc = 0.f;
    for (int i = 0; i < 64; ++i) acc += Wq[t * 64 + i] * xp_s[i];
    t1[t] = acc;
    __syncthreads();
    float acc2 = 0.f;
    for (int i = 0; i < 64; ++i) acc2 += Wup[t * 64 + i] * t1[i];
    float m = acc2;
#pragma unroll
    for (int off = 32; off; off >>= 1) m = fmaxf(m, __shfl_xor(m, off, 64));
    float e = __expf(acc2 - m);
    float ssum = e;
#pragma unroll
    for (int off = 32; off; off >>= 1) ssum += __shfl_xor(ssum, off, 64);
    float av = e / ssum;
    ws[WS_A + b * 64 + t] = av;
    a_s[t] = av;
    __syncthreads();
    float wav = 0.f;
    for (int o = 0; o < 64; ++o) wav += a_s[o] * Wq[o * 64 + t];
    ws[WS_WA + b * 64 + t] = wav;
    __syncthreads();
  }
}

// K2b: block 0 -> M1 = Wout@Wv_spa ; block j=1..8 -> M2[b=j-1] = Wout@diag(a[b])@Wv_spe
__global__ __launch_bounds__(256) void k2b(const float* __restrict__ Wout, const float* __restrict__ Wv_spa,
                                           const float* __restrict__ Wv_spe, float* __restrict__ ws) {
  __shared__ float A[4096], Bm[4096];
  int j = blockIdx.x;
  for (int idx = threadIdx.x; idx < 4096; idx += 256) {
    A[idx] = Wout[idx];
    if (j == 0)
      Bm[idx] = Wv_spa[idx];
    else
      Bm[idx] = ws[WS_A + (j - 1) * 64 + (idx >> 6)] * Wv_spe[idx];
  }
  __syncthreads();
  float* dst = (j == 0) ? (ws + WS_M1) : (ws + WS_M2 + (size_t)(j - 1) * 4096);
  for (int oi = threadIdx.x; oi < 4096; oi += 256) {
    int o = oi >> 6, i = oi & 63;
    float acc = 0.f;
#pragma unroll
    for (int c = 0; c < 64; ++c) acc += A[o * 64 + c] * Bm[c * 64 + i];
    dst[oi] = acc;
  }
}

// K3: attn_spa[b,n] = wa[b] . x[b,:,n] -> out plane(b,2); grid 1024, 2 px/thread
__global__ __launch_bounds__(256) void k3(const float* __restrict__ x, const float* __restrict__ ws,
                                          float* __restrict__ out) {
  int blk = blockIdx.x;
  int b = blk >> 7;
  int base = (blk & 127) << 9;
  int n0 = base + threadIdx.x * 2;
  const float* xb = x + (size_t)b * Cn * HWn;
  const float* wa = ws + WS_WA + b * 64;
  float kx = 0.f, ky = 0.f;
#pragma unroll
  for (int c = 0; c < Cn; ++c) {
    float2 xv = *(const float2*)(xb + (size_t)c * HWn + n0);
    float w = wa[c];
    kx += w * xv.x; ky += w * xv.y;
  }
  float2 r = {kx, ky};
  *(float2*)(out + ((size_t)(b * Cn + 2)) * HWn + n0) = r;
}

// Kconv: s = sigmoid(conv7x7(attn_spa)); read out plane(b,2), write dst_base + b*dst_stride
__global__ __launch_bounds__(256) void kconv(const float* __restrict__ Wn, const float* __restrict__ out,
                                             float* __restrict__ dst_base, size_t dst_stride) {
  __shared__ float t[38 * 38];
  int blk = blockIdx.x;
  int b = blk >> 6, ty = (blk >> 3) & 7, tx = blk & 7;
  const float* src = out + ((size_t)(b * Cn + 2)) * HWn;
  float* dstp = dst_base + (size_t)b * dst_stride;
  for (int idx = threadIdx.x; idx < 38 * 38; idx += 256) {
    int ly = idx / 38, lx = idx - ly * 38;
    int gy = ty * 32 + ly - 3, gx = tx * 32 + lx - 3;
    float v = 0.f;
    if (gy >= 0 && gy < 256 && gx >= 0 && gx < 256) v = src[gy * 256 + gx];
    t[idx] = v;
  }
  __syncthreads();
#pragma unroll
  for (int q = 0; q < 4; ++q) {
    int pix = threadIdx.x + q * 256;
    int r = pix >> 5, col = pix & 31;
    float acc = 0.f;
#pragma unroll
    for (int dy = 0; dy < 7; ++dy)
#pragma unroll
      for (int dx = 0; dx < 7; ++dx)
        acc += t[(r + dy) * 38 + (col + dx)] * Wn[dy * 7 + dx];
    float sg = 1.f / (1.f + __expf(-acc));
    dstp[(ty * 32 + r) * 256 + tx * 32 + col] = sg;
  }
}

// K4 fast: grid 2048 = b(8) x tile(64) x oc(4). Each block: 16 outputs x 1024 px.
// s read from ws (no races). LDS 8KB -> high occupancy.
__global__ __launch_bounds__(256, 4) void k4f(const float* __restrict__ x, const float* __restrict__ ws,
                                              float* __restrict__ out) {
  __shared__ float M1T[64 * 16];
  __shared__ float M2T[64 * 16];
  int blk = blockIdx.x;
  int oc = blk & 3;
  int tile = (blk >> 2) & 63;
  int b = blk >> 8;
  int t = threadIdx.x;
  const float* m1g = ws + WS_M1 + oc * 1024;
  const float* m2g = ws + WS_M2 + (size_t)b * 4096 + oc * 1024;
  for (int idx = t; idx < 1024; idx += 256) {
    int o = idx >> 6, i = idx & 63;
    M1T[i * 16 + o] = m1g[idx];
    M2T[i * 16 + o] = m2g[idx];
  }
  __syncthreads();

  int n0 = (tile << 10) + t * 4;
  const float* xb = x + (size_t)b * Cn * HWn;
  float4 s4 = *(const float4*)(ws + WS_S + (size_t)b * HWn + n0);
  float4 acc[16];
#pragma unroll
  for (int o = 0; o < 16; ++o) acc[o] = make_float4(0.f, 0.f, 0.f, 0.f);

  for (int i = 0; i < 64; ++i) {
    float4 xv = *(const float4*)(xb + (size_t)i * HWn + n0);
    float4 sx;
    sx.x = s4.x * xv.x; sx.y = s4.y * xv.y; sx.z = s4.z * xv.z; sx.w = s4.w * xv.w;
    const float4* m1q = (const float4*)(M1T + i * 16);
    const float4* m2q = (const float4*)(M2T + i * 16);
#pragma unroll
    for (int g = 0; g < 4; ++g) {
      float4 w1 = m1q[g], w2 = m2q[g];
      acc[g * 4 + 0].x += w1.x * sx.x + w2.x * xv.x;
      acc[g * 4 + 0].y += w1.x * sx.y + w2.x * xv.y;
      acc[g * 4 + 0].z += w1.x * sx.z + w2.x * xv.z;
      acc[g * 4 + 0].w += w1.x * sx.w + w2.x * xv.w;
      acc[g * 4 + 1].x += w1.y * sx.x + w2.y * xv.x;
      acc[g * 4 + 1].y += w1.y * sx.y + w2.y * xv.y;
      acc[g * 4 + 1].z += w1.y * sx.z + w2.y * xv.z;
      acc[g * 4 + 1].w += w1.y * sx.w + w2.y * xv.w;
      acc[g * 4 + 2].x += w1.z * sx.x + w2.z * xv.x;
      acc[g * 4 + 2].y += w1.z * sx.y + w2.z * xv.y;
      acc[g * 4 + 2].z += w1.z * sx.z + w2.z * xv.z;
      acc[g * 4 + 2].w += w1.z * sx.w + w2.z * xv.w;
      acc[g * 4 + 3].x += w1.w * sx.x + w2.w * xv.x;
      acc[g * 4 + 3].y += w1.w * sx.y + w2.w * xv.y;
      acc[g * 4 + 3].z += w1.w * sx.z + w2.w * xv.z;
      acc[g * 4 + 3].w += w1.w * sx.w + w2.w * xv.w;
    }
  }
  float* op = out + ((size_t)(b * Cn + oc * 16)) * HWn + n0;
#pragma unroll
  for (int o = 0; o < 16; ++o)
    *(float4*)(op + (size_t)o * HWn) = acc[o];
}

// K4 mono fallback (ws too small for s buffer): oc loop in-block, s owner-read from plane(b,0)
#define MSTRIDE 68
__global__ __launch_bounds__(256) void k4m(const float* __restrict__ x, const float* __restrict__ ws,
                                           float* out) {
  __shared__ float M1T[64 * MSTRIDE];
  __shared__ float M2T[64 * MSTRIDE];
  int blk = blockIdx.x;
  int b = blk >> 6;
  int base = (blk & 63) << 10;
  int t = threadIdx.x;
  const float* m1g = ws + WS_M1;
  const float* m2g = ws + WS_M2 + (size_t)b * 4096;
  for (int idx = t; idx < 4096; idx += 256) {
    int o = idx >> 6, i = idx & 63;
    M1T[i * MSTRIDE + o] = m1g[idx];
    M2T[i * MSTRIDE + o] = m2g[idx];
  }
  __syncthreads();
  int n0 = base + t * 4;
  const float* xb = x + (size_t)b * Cn * HWn;
  float* op = out + ((size_t)(b * Cn)) * HWn + n0;
  float4 s4 = *(const float4*)op;
#pragma unroll
  for (int oc = 0; oc < 4; ++oc) {
    float4 acc[16];
#pragma unroll
    for (int o = 0; o < 16; ++o) acc[o] = make_float4(0.f, 0.f, 0.f, 0.f);
    for (int i = 0; i < 64; ++i) {
      float4 xv = *(const float4*)(xb + (size_t)i * HWn + n0);
      float4 sx;
      sx.x = s4.x * xv.x; sx.y = s4.y * xv.y; sx.z = s4.z * xv.z; sx.w = s4.w * xv.w;
      const float* m1r = M1T + i * MSTRIDE + oc * 16;
      const float* m2r = M2T + i * MSTRIDE + oc * 16;
#pragma unroll
      for (int o = 0; o < 16; ++o) {
        float m1 = m1r[o], m2 = m2r[o];
        acc[o].x += m1 * sx.x + m2 * xv.x;
        acc[o].y += m1 * sx.y + m2 * xv.y;
        acc[o].z += m1 * sx.z + m2 * xv.z;
        acc[o].w += m1 * sx.w + m2 * xv.w;
      }
    }
#pragma unroll
    for (int o = 0; o < 16; ++o)
      *(float4*)(op + (size_t)(oc * 16 + o) * HWn) = acc[o];
  }
}

extern "C" void kernel_launch(void* const* d_in, const int* in_sizes, int n_in,
                              void* d_out, int out_size, void* d_ws, size_t ws_size,
                              hipStream_t stream) {
  const float* x      = (const float*)d_in[0];
  const float* Wq     = (const float*)d_in[1];
  const float* Wk     = (const float*)d_in[2];
  const float* Wv_spe = (const float*)d_in[3];
  const float* Wv_spa = (const float*)d_in[4];
  const float* Wup    = (const float*)d_in[5];
  const float* Wout   = (const float*)d_in[6];
  const float* Wn     = (const float*)d_in[7];
  float* out = (float*)d_out;
  float* ws  = (float*)d_ws;

  bool fast = ws_size >= (size_t)(WS_S + Bn * HWn) * sizeof(float);

  hipMemsetAsync(ws, 0, 520 * sizeof(float), stream);  // Z + xpool accumulators
  k1<<<1024, 256, 0, stream>>>(x, Wk, ws);
  k2a<<<1, 64, 0, stream>>>(Wq, Wup, ws);
  k2b<<<9, 256, 0, stream>>>(Wout, Wv_spa, Wv_spe, ws);
  k3<<<1024, 256, 0, stream>>>(x, ws, out);
  if (fast) {
    kconv<<<512, 256, 0, stream>>>(Wn, out, ws + WS_S, (size_t)HWn);
    k4f<<<2048, 256, 0, stream>>>(x, ws, out);
  } else {
    kconv<<<512, 256, 0, stream>>>(Wn, out, out, (size_t)Cn * HWn);
    k4m<<<512, 256, 0, stream>>>(x, ws, out);
  }
}